// Round 3
// baseline (341.870 us; speedup 1.0000x reference)
//
#include <hip/hip_runtime.h>

// Problem constants (fixed by the reference)
#define B_ROWS   512
#define C_COLS   65536
#define BR       4                    // rows per block
#define CCH      4096                 // columns per chunk
#define NCH      (C_COLS / CCH)       // 16 chunks per row
#define RG       (B_ROWS / BR)        // 128 row-groups
#define NBLK     (RG * NCH)           // 2048 blocks
#define T1       256                  // threads
#define ITERS    (CCH / 4 / T1)       // 4 float4 per thread per stream

// ws layout:
//   [0, 128 KiB)  : float4 part[B_ROWS][NCH]  {num, a2, b2, bce}
//   [128K, +64B)  : float wsum[NCH]           per-chunk sum of bce_weights
//   [128K+128B]   : uint counter              (zeroed by memset node each launch)
#define WS_PART_F4   (B_ROWS * NCH)
#define WS_WSUM_OFF  (WS_PART_F4 * 16)            // bytes
#define WS_CTR_OFF   (WS_WSUM_OFF + 128)          // bytes

__device__ __forceinline__ void wave_reduce4(float& a, float& b, float& c, float& d) {
    #pragma unroll
    for (int off = 32; off >= 1; off >>= 1) {
        a += __shfl_down(a, off);
        b += __shfl_down(b, off);
        c += __shfl_down(c, off);
        d += __shfl_down(d, off);
    }
}

__global__ __launch_bounds__(T1) void coscel_fused(
    const float* __restrict__ pred,
    const float* __restrict__ tgt,
    const float* __restrict__ cw,
    const float* __restrict__ bw,
    float4* __restrict__ part,
    float*  __restrict__ wsum,
    unsigned int* __restrict__ counter,
    float* __restrict__ out)
{
    const int blk  = blockIdx.x;          // 0 .. NBLK-1
    const int rowg = blk / NCH;
    const int ch   = blk % NCH;
    const int tid  = threadIdx.x;

    const int row0 = rowg * BR;
    const size_t cbase = (size_t)ch * CCH;

    const float4* __restrict__ w4 = (const float4*)(cw + cbase);
    const float4* __restrict__ g4 = (const float4*)(bw + cbase);
    const float4* p4[BR];
    const float4* t4[BR];
    #pragma unroll
    for (int r = 0; r < BR; ++r) {
        p4[r] = (const float4*)(pred + (size_t)(row0 + r) * C_COLS + cbase);
        t4[r] = (const float4*)(tgt  + (size_t)(row0 + r) * C_COLS + cbase);
    }

    float num[BR], a2[BR], b2[BR], bce[BR];
    #pragma unroll
    for (int r = 0; r < BR; ++r) { num[r] = a2[r] = b2[r] = bce[r] = 0.f; }
    float gsum = 0.f;

    #pragma unroll 2
    for (int i = 0; i < ITERS; ++i) {
        const int idx = i * T1 + tid;     // coalesced
        const float4 w = w4[idx];
        const float4 g = g4[idx];
        gsum += g.x + g.y + g.z + g.w;

        float4 pv[BR], tv[BR];
        #pragma unroll
        for (int r = 0; r < BR; ++r) { pv[r] = p4[r][idx]; tv[r] = t4[r][idx]; }

        const float4 w2 = make_float4(w.x * w.x, w.y * w.y, w.z * w.z, w.w * w.w);

        #pragma unroll
        for (int r = 0; r < BR; ++r) {
            #define DO_COMP(comp)                                            \
            {                                                                \
                const float x  = tv[r].comp, y = pv[r].comp;                 \
                const float xy = x * y;                                      \
                num[r] = fmaf(xy,    w2.comp, num[r]);                       \
                a2[r]  = fmaf(x * x, w2.comp, a2[r]);                        \
                b2[r]  = fmaf(y * y, w2.comp, b2[r]);                        \
                const float e = __expf(-fabsf(x));                           \
                const float l = __logf(1.0f + e);                            \
                bce[r] += g.comp * (fmaxf(x, 0.0f) - xy + l);                \
            }
            DO_COMP(x) DO_COMP(y) DO_COMP(z) DO_COMP(w)
            #undef DO_COMP
        }
    }

    // Per-wave reduce, then cross-wave via LDS, tid0 stores partials.
    #pragma unroll
    for (int r = 0; r < BR; ++r) wave_reduce4(num[r], a2[r], b2[r], bce[r]);
    #pragma unroll
    for (int off = 32; off >= 1; off >>= 1) gsum += __shfl_down(gsum, off);

    __shared__ float4 sred[T1 / 64][BR];
    __shared__ float  sg[T1 / 64];
    const int lane = tid & 63, wid = tid >> 6;
    if (lane == 0) {
        #pragma unroll
        for (int r = 0; r < BR; ++r) sred[wid][r] = make_float4(num[r], a2[r], b2[r], bce[r]);
        sg[wid] = gsum;
    }
    __syncthreads();
    if (tid == 0) {
        #pragma unroll
        for (int r = 0; r < BR; ++r) {
            float4 acc = sred[0][r];
            #pragma unroll
            for (int w_ = 1; w_ < T1 / 64; ++w_) {
                const float4 s = sred[w_][r];
                acc.x += s.x; acc.y += s.y; acc.z += s.z; acc.w += s.w;
            }
            part[(size_t)(row0 + r) * NCH + ch] = acc;
        }
        if (rowg == 0) wsum[ch] = sg[0] + sg[1] + sg[2] + sg[3];
    }

    // ---- last-block-done: one block folds everything ----
    __shared__ unsigned int is_last;
    __threadfence();                       // release our stores (device scope)
    if (tid == 0) {
        const unsigned int old = __hip_atomic_fetch_add(
            counter, 1u, __ATOMIC_ACQ_REL, __HIP_MEMORY_SCOPE_AGENT);
        is_last = (old == (unsigned int)(NBLK - 1));
    }
    __syncthreads();
    if (!is_last) return;
    __threadfence();                       // acquire: invalidate stale L2 lines

    // Finisher: 256 threads fold 512 rows (2 rows each) in fixed order.
    float cos_acc = 0.f, bce_acc = 0.f;
    #pragma unroll
    for (int rr = 0; rr < B_ROWS / T1; ++rr) {
        const int r = rr * T1 + tid;
        float n = 0.f, aa = 0.f, bb = 0.f, bc = 0.f;
        #pragma unroll
        for (int c = 0; c < NCH; ++c) {
            const float4 v = part[(size_t)r * NCH + c];
            n += v.x; aa += v.y; bb += v.z; bc += v.w;
        }
        const float na = fmaxf(sqrtf(aa), 1e-8f);
        const float nb = fmaxf(sqrtf(bb), 1e-8f);
        cos_acc += n / (na * nb);
        bce_acc += bc;
    }
    float wsv = (tid < NCH) ? wsum[tid] : 0.f;

    #pragma unroll
    for (int off = 32; off >= 1; off >>= 1) {
        cos_acc += __shfl_down(cos_acc, off);
        bce_acc += __shfl_down(bce_acc, off);
        wsv     += __shfl_down(wsv, off);
    }
    __shared__ float s0[T1 / 64], s1[T1 / 64], s2[T1 / 64];
    if (lane == 0) { s0[wid] = cos_acc; s1[wid] = bce_acc; s2[wid] = wsv; }
    __syncthreads();
    if (tid == 0) {
        float cs = 0.f, bs = 0.f, wss = 0.f;
        #pragma unroll
        for (int i = 0; i < T1 / 64; ++i) { cs += s0[i]; bs += s1[i]; wss += s2[i]; }
        const float cosine_loss = -(cs / (float)B_ROWS);
        const float sub_graph   = bs / (wss + 1e-10f);
        out[0] = cosine_loss + sub_graph / 10.0f;
    }
}

extern "C" void kernel_launch(void* const* d_in, const int* in_sizes, int n_in,
                              void* d_out, int out_size, void* d_ws, size_t ws_size,
                              hipStream_t stream) {
    const float* pred = (const float*)d_in[0];   // prediction (B, C)
    const float* tgt  = (const float*)d_in[1];   // target     (B, C)
    const float* cw   = (const float*)d_in[2];   // cos_weights (C,)
    const float* bw   = (const float*)d_in[3];   // bce_weights (C,)
    float* out = (float*)d_out;

    char* ws = (char*)d_ws;
    float4*       part    = (float4*)ws;
    float*        wsum    = (float*)(ws + WS_WSUM_OFF);
    unsigned int* counter = (unsigned int*)(ws + WS_CTR_OFF);

    // Zero the arrival counter every launch (graph-legal memset node).
    hipMemsetAsync(counter, 0, sizeof(unsigned int), stream);

    coscel_fused<<<NBLK, T1, 0, stream>>>(pred, tgt, cw, bw, part, wsum, counter, out);
}

// Round 4
// 58.353 us; speedup vs baseline: 5.8586x; 5.8586x over previous
//
#include <hip/hip_runtime.h>

// Problem constants (fixed by the reference)
#define B_ROWS   512
#define C_COLS   65536
#define BR       4                    // rows per block
#define CCH      4096                 // columns per chunk
#define NCH      (C_COLS / CCH)       // 16 chunks per row
#define RG       (B_ROWS / BR)        // 128 row-groups
#define T1       256                  // threads, kernel 1
#define ITERS    (CCH / 4 / T1)       // 4 float4 per thread per stream
#define T2       512                  // threads, kernel 2 (== B_ROWS)

// ws layout: [0 .. B_ROWS*NCH) float4 row-chunk partials {num,a2,b2,bce}
//            then NCH floats: per-chunk sum of bce_weights
#define WS_F4_COUNT (B_ROWS * NCH)

__device__ __forceinline__ void wave_reduce4(float& a, float& b, float& c, float& d) {
    #pragma unroll
    for (int off = 32; off >= 1; off >>= 1) {
        a += __shfl_down(a, off);
        b += __shfl_down(b, off);
        c += __shfl_down(c, off);
        d += __shfl_down(d, off);
    }
}

// Kernel 1: each block = 4 rows x one 4096-col chunk, register-double-buffered.
__global__ __launch_bounds__(T1) void coscel_partial(
    const float* __restrict__ pred,
    const float* __restrict__ tgt,
    const float* __restrict__ cw,
    const float* __restrict__ bw,
    float4* __restrict__ ws)
{
    const int blk  = blockIdx.x;          // 0 .. RG*NCH-1 (2048)
    const int rowg = blk / NCH;
    const int ch   = blk % NCH;
    const int tid  = threadIdx.x;

    const int row0 = rowg * BR;
    const size_t cbase = (size_t)ch * CCH;

    const float4* __restrict__ w4 = (const float4*)(cw + cbase);
    const float4* __restrict__ g4 = (const float4*)(bw + cbase);
    const float4* p4[BR];
    const float4* t4[BR];
    #pragma unroll
    for (int r = 0; r < BR; ++r) {
        p4[r] = (const float4*)(pred + (size_t)(row0 + r) * C_COLS + cbase);
        t4[r] = (const float4*)(tgt  + (size_t)(row0 + r) * C_COLS + cbase);
    }

    float num[BR], a2[BR], b2[BR], bce[BR];
    #pragma unroll
    for (int r = 0; r < BR; ++r) { num[r] = a2[r] = b2[r] = bce[r] = 0.f; }
    float gsum = 0.f;

    // Prologue: load iteration 0 into the current register set.
    float4 w_c = w4[tid];
    float4 g_c = g4[tid];
    float4 pv_c[BR], tv_c[BR];
    #pragma unroll
    for (int r = 0; r < BR; ++r) { pv_c[r] = p4[r][tid]; tv_c[r] = t4[r][tid]; }

    #pragma unroll
    for (int i = 0; i < ITERS; ++i) {
        // Prefetch next iteration while computing on the current one.
        float4 w_n, g_n, pv_n[BR], tv_n[BR];
        if (i + 1 < ITERS) {
            const int nidx = (i + 1) * T1 + tid;
            w_n = w4[nidx];
            g_n = g4[nidx];
            #pragma unroll
            for (int r = 0; r < BR; ++r) { pv_n[r] = p4[r][nidx]; tv_n[r] = t4[r][nidx]; }
        }

        if (rowg == 0)   // block-uniform: only chunk-owner blocks sum bce_weights
            gsum += g_c.x + g_c.y + g_c.z + g_c.w;

        const float4 w2 = make_float4(w_c.x * w_c.x, w_c.y * w_c.y,
                                      w_c.z * w_c.z, w_c.w * w_c.w);
        #pragma unroll
        for (int r = 0; r < BR; ++r) {
            #define DO_COMP(comp)                                            \
            {                                                                \
                const float x  = tv_c[r].comp, y = pv_c[r].comp;             \
                const float xy = x * y;                                      \
                num[r] = fmaf(xy,    w2.comp, num[r]);                       \
                a2[r]  = fmaf(x * x, w2.comp, a2[r]);                        \
                b2[r]  = fmaf(y * y, w2.comp, b2[r]);                        \
                const float e = __expf(-fabsf(x));                           \
                const float l = __logf(1.0f + e);                            \
                bce[r] += g_c.comp * (fmaxf(x, 0.0f) - xy + l);              \
            }
            DO_COMP(x) DO_COMP(y) DO_COMP(z) DO_COMP(w)
            #undef DO_COMP
        }

        if (i + 1 < ITERS) {
            w_c = w_n; g_c = g_n;
            #pragma unroll
            for (int r = 0; r < BR; ++r) { pv_c[r] = pv_n[r]; tv_c[r] = tv_n[r]; }
        }
    }

    // Reduce each row's 4 values across the wave (+gsum for rowg==0).
    #pragma unroll
    for (int r = 0; r < BR; ++r) wave_reduce4(num[r], a2[r], b2[r], bce[r]);
    if (rowg == 0) {
        #pragma unroll
        for (int off = 32; off >= 1; off >>= 1) gsum += __shfl_down(gsum, off);
    }

    __shared__ float4 sred[T1 / 64][BR];
    __shared__ float  sg[T1 / 64];
    const int lane = tid & 63, wid = tid >> 6;
    if (lane == 0) {
        #pragma unroll
        for (int r = 0; r < BR; ++r) sred[wid][r] = make_float4(num[r], a2[r], b2[r], bce[r]);
        sg[wid] = gsum;
    }
    __syncthreads();
    if (tid == 0) {
        #pragma unroll
        for (int r = 0; r < BR; ++r) {
            float4 acc = sred[0][r];
            #pragma unroll
            for (int w_ = 1; w_ < T1 / 64; ++w_) {
                const float4 s = sred[w_][r];
                acc.x += s.x; acc.y += s.y; acc.z += s.z; acc.w += s.w;
            }
            ws[(size_t)(row0 + r) * NCH + ch] = acc;
        }
        if (rowg == 0) {
            ((float*)(ws + WS_F4_COUNT))[ch] = sg[0] + sg[1] + sg[2] + sg[3];
        }
    }
}

// Kernel 2: fold chunk partials per row, cosine per row, global sums, final scalar.
__global__ __launch_bounds__(T2) void coscel_final(
    const float4* __restrict__ ws,
    float* __restrict__ out)
{
    const int tid = threadIdx.x;    // == row

    float num = 0.f, a2 = 0.f, b2 = 0.f, bce = 0.f;
    #pragma unroll
    for (int c = 0; c < NCH; ++c) {
        const float4 v = ws[(size_t)tid * NCH + c];
        num += v.x; a2 += v.y; b2 += v.z; bce += v.w;
    }
    const float na = fmaxf(sqrtf(a2), 1e-8f);
    const float nb = fmaxf(sqrtf(b2), 1e-8f);
    float cosv = num / (na * nb);

    const float* wpart = (const float*)(ws + WS_F4_COUNT);
    float wsum = (tid < NCH) ? wpart[tid] : 0.f;

    #pragma unroll
    for (int off = 32; off >= 1; off >>= 1) {
        cosv += __shfl_down(cosv, off);
        bce  += __shfl_down(bce,  off);
        wsum += __shfl_down(wsum, off);
    }
    __shared__ float s0[T2 / 64], s1[T2 / 64], s2[T2 / 64];
    const int lane = tid & 63, wid = tid >> 6;
    if (lane == 0) { s0[wid] = cosv; s1[wid] = bce; s2[wid] = wsum; }
    __syncthreads();
    if (tid == 0) {
        float cs = 0.f, bs = 0.f, wss = 0.f;
        #pragma unroll
        for (int i = 0; i < T2 / 64; ++i) { cs += s0[i]; bs += s1[i]; wss += s2[i]; }
        const float cosine_loss = -(cs / (float)B_ROWS);
        const float sub_graph   = bs / (wss + 1e-10f);
        out[0] = cosine_loss + sub_graph / 10.0f;
    }
}

extern "C" void kernel_launch(void* const* d_in, const int* in_sizes, int n_in,
                              void* d_out, int out_size, void* d_ws, size_t ws_size,
                              hipStream_t stream) {
    const float* pred = (const float*)d_in[0];   // prediction (B, C)
    const float* tgt  = (const float*)d_in[1];   // target     (B, C)
    const float* cw   = (const float*)d_in[2];   // cos_weights (C,)
    const float* bw   = (const float*)d_in[3];   // bce_weights (C,)
    float* out = (float*)d_out;
    float4* ws = (float4*)d_ws;                  // 128 KiB partials + 64 B wsum

    coscel_partial<<<RG * NCH, T1, 0, stream>>>(pred, tgt, cw, bw, ws);
    coscel_final<<<1, T2, 0, stream>>>(ws, out);
}